// Round 7
// baseline (105.360 us; speedup 1.0000x reference)
//
#include <hip/hip_runtime.h>
#include <stdint.h>

#define UNITS  4096
#define TPB    128            // 2 waves per block, one row per block
#define EPT    (UNITS / TPB)  // 32 elements per thread
#define CAP    320            // window count ~242 +- 15; cap = +5.2 sigma
#define NSLOT  (CAP / 64)     // 5 slots per lane in the select
#define LOF    0.44f          // theta ~= 0.5244 +- 0.0206 ; [LO,HI) = +-4 sigma
#define HIF    0.61f
#define SELBITS 22            // bits(HIF)-bits(LOF) = 0x3AE148 < 2^22

// LDS-only barrier (no vmcnt drain)
__device__ __forceinline__ void lds_barrier() {
    asm volatile("s_waitcnt lgkmcnt(0)" ::: "memory");
    __builtin_amdgcn_s_barrier();
}

__device__ __forceinline__ uint32_t flipu(uint32_t b) {
    return b ^ (uint32_t)(((int32_t)b >> 31) | (int32_t)0x80000000);
}

// popcount of mask bits strictly below this lane
__device__ __forceinline__ uint32_t mbcnt64(uint64_t m) {
    return __builtin_amdgcn_mbcnt_hi((uint32_t)(m >> 32),
           __builtin_amdgcn_mbcnt_lo((uint32_t)m, 0u));
}

__global__ __launch_bounds__(TPB, 8) void ksparse_select_kernel(
        const float* __restrict__ X, float* __restrict__ out, int kidx) {
    __shared__ uint32_t list[CAP];  // 1.25 KiB
    __shared__ uint32_t cnt;
    __shared__ uint32_t wnb[2];     // per-wave count below LO
    __shared__ uint32_t fbc[2];     // fallback per-wave counts

    const int t    = threadIdx.x;
    const int w    = t >> 6;
    const int lane = t & 63;

    if (t == 0) cnt = 0u;

    // load row: 8 x float4 per thread (256 KB in flight per CU at 16 blocks)
    float f[EPT];
    {
        const float4* Xv = reinterpret_cast<const float4*>(X + (size_t)blockIdx.x * UNITS);
#pragma unroll
        for (int j = 0; j < EPT / 4; ++j) {
            float4 v = Xv[j * TPB + t];
            f[4 * j + 0] = v.x; f[4 * j + 1] = v.y;
            f[4 * j + 2] = v.z; f[4 * j + 3] = v.w;
        }
    }

    lds_barrier();  // cnt zeroed everywhere

    // pass 1: wave totals (ballot + scalar popcounts only)
    uint32_t nbw = 0, wtot = 0;
#pragma unroll
    for (int e = 0; e < EPT; ++e) {
        const uint64_t mlo = __ballot(f[e] < LOF);
        const uint64_t mhi = __ballot(f[e] < HIF);
        nbw  += (uint32_t)__popcll(mlo);
        wtot += (uint32_t)__popcll(mhi & ~mlo);
    }
    if (lane == 0) wnb[w] = nbw;

    // reserve list space (one atomic per wave), pass 2: ballot-ranked scatter
    uint32_t base = 0;
    if (lane == 0) base = atomicAdd(&cnt, wtot);
    base = __shfl(base, 0);
    uint32_t pfx = 0;
#pragma unroll
    for (int e = 0; e < EPT; ++e) {
        const bool lo = f[e] < LOF;
        const bool hi = f[e] < HIF;
        const uint64_t mlo = __ballot(lo);
        const uint64_t mhi = __ballot(hi);
        const uint64_t mwin = mhi & ~mlo;
        if (hi && !lo) {
            const uint32_t idx = base + pfx + mbcnt64(mwin);
            if (idx < CAP) list[idx] = __float_as_uint(f[e]);  // positive: bits order-preserving
        }
        pfx += (uint32_t)__popcll(mwin);
    }

    lds_barrier();  // list + cnt + wnb visible

    const uint32_t c  = cnt;
    const uint32_t cb = wnb[0] + wnb[1];
    const uint32_t k  = (uint32_t)kidx;

    float4* Ov = reinterpret_cast<float4*>(out + (size_t)blockIdx.x * UNITS);

    if (cb <= k && k < cb + c && c <= CAP) {     // block-uniform bracket check
        const uint32_t r   = k - cb;             // rank of theta within the list
        const uint32_t LOu = __float_as_uint(LOF);

        // both waves redundantly load the list (rebased 22-bit keys), sentinel-padded
        uint32_t sv[NSLOT];
#pragma unroll
        for (int i = 0; i < NSLOT; ++i) {
            const uint32_t ix = (uint32_t)lane + 64u * i;
            sv[i] = (ix < c) ? (list[ix] - LOu) : 0xFFFFFFFFu;
        }

        // MSB-first ballot radix select over 22 bits (wave-local, no barriers)
        uint32_t p = 0;
#pragma unroll
        for (int b = SELBITS - 1; b >= 0; --b) {
            const uint32_t mid = p | (1u << b);
            uint32_t cm = 0;
#pragma unroll
            for (int i = 0; i < NSLOT; ++i)
                cm += (uint32_t)__popcll(__ballot(sv[i] < mid));
            if (cm <= r) p = mid;   // wave-uniform
        }
        const float th = __uint_as_float(LOu + p);  // exact bits of theta

#pragma unroll
        for (int j = 0; j < EPT / 4; ++j) {
            float4 o;
            o.x = (f[4 * j + 0] >= th) ? f[4 * j + 0] : 0.0f;
            o.y = (f[4 * j + 1] >= th) ? f[4 * j + 1] : 0.0f;
            o.z = (f[4 * j + 2] >= th) ? f[4 * j + 2] : 0.0f;
            o.w = (f[4 * j + 3] >= th) ? f[4 * j + 3] : 0.0f;
            Ov[j * TPB + t] = o;
        }
    } else {
        // exact block-wide fallback (expected ~1 row per dataset): 32-bit
        // bit-search in flipped space; flipu recomputed inline to keep the
        // hot path's register set unchanged.
        uint32_t p = 0;
#pragma unroll 1
        for (int b = 31; b >= 0; --b) {
            const uint32_t mid = p | (1u << b);
            uint32_t cw = 0;
#pragma unroll
            for (int e = 0; e < EPT; ++e)
                cw += (uint32_t)__popcll(__ballot(flipu(__float_as_uint(f[e])) < mid));
            if (lane == 0) fbc[w] = cw;
            lds_barrier();
            const uint32_t cm = fbc[0] + fbc[1];
            if (cm <= k) p = mid;   // block-uniform
            lds_barrier();          // fbc consumed before next overwrite
        }
#pragma unroll
        for (int j = 0; j < EPT / 4; ++j) {
            float4 o;
            o.x = (flipu(__float_as_uint(f[4 * j + 0])) >= p) ? f[4 * j + 0] : 0.0f;
            o.y = (flipu(__float_as_uint(f[4 * j + 1])) >= p) ? f[4 * j + 1] : 0.0f;
            o.z = (flipu(__float_as_uint(f[4 * j + 2])) >= p) ? f[4 * j + 2] : 0.0f;
            o.w = (flipu(__float_as_uint(f[4 * j + 3])) >= p) ? f[4 * j + 3] : 0.0f;
            Ov[j * TPB + t] = o;
        }
    }
}

extern "C" void kernel_launch(void* const* d_in, const int* in_sizes, int n_in,
                              void* d_out, int out_size, void* d_ws, size_t ws_size,
                              hipStream_t stream) {
    const float* X = (const float*)d_in[0];
    float* out = (float*)d_out;
    const int rows = in_sizes[0] / UNITS;
    const int kidx = (int)(0.7 * UNITS);  // 2867
    ksparse_select_kernel<<<rows, TPB, 0, stream>>>(X, out, kidx);
}